// Round 1
// baseline (517.386 us; speedup 1.0000x reference)
//
#include <hip/hip_runtime.h>

#define B_ 32
#define T_ 1024
#define V_ 1024
#define L_ 256
#define S_ 513
#define NEG_ (-1e30f)

// v_exp_f32 / v_log_f32 are base-2 natively.
#if __has_builtin(__builtin_amdgcn_exp2f)
__device__ __forceinline__ float ex2(float x) { return __builtin_amdgcn_exp2f(x); }
#else
__device__ __forceinline__ float ex2(float x) { return exp2f(x); }
#endif
#if __has_builtin(__builtin_amdgcn_logf)
__device__ __forceinline__ float lg2(float x) { return __builtin_amdgcn_logf(x); }
#else
__device__ __forceinline__ float lg2(float x) { return log2f(x); }
#endif

__global__ void ctc_zero(float* out) { out[0] = 0.0f; }

// One block per batch element. Thread tid owns state tid; thread 511 also owns
// state 512. Alpha double-buffered in LDS, state s stored at index s+2 so the
// s-1 / s-2 reads hit NEG pads instead of going out of range.
__global__ __launch_bounds__(512) void ctc_fwd(const float* __restrict__ lp,
                                               const int* __restrict__ tgt,
                                               const int* __restrict__ ilen,
                                               const int* __restrict__ tlen,
                                               float* __restrict__ out) {
  __shared__ float As[2][520];

  const int b = blockIdx.x;
  const int tid = threadIdx.x;
  const int len = ilen[b];
  const int tl = tlen[b];
  const float* gp = lp + (size_t)b * T_ * V_;
  const int s = tid;
  const bool two = (tid == 511);  // also handles state 512 (blank)

  int col;
  bool skip;
  if (s & 1) {
    const int l = s >> 1;
    col = tgt[b * L_ + l];
    skip = (s >= 3) && (col != tgt[b * L_ + l - 1]);
  } else {
    col = 0;  // blank
    skip = false;
  }

  const float L2E = 1.4426950408889634f;  // log2(e)

  // t = 0 init (log2 domain)
  As[0][tid + 2] = (s < 2) ? L2E * gp[col] : NEG_;
  if (two) As[0][514] = NEG_;
  if (tid < 2) { As[0][tid] = NEG_; As[1][tid] = NEG_; }
  __syncthreads();

  const float* g1 = gp + col;  // per-thread gather column (fixed across t)

  // 4-step-deep software-pipelined prefetch of lp[t][col]
  float cur0 = g1[(size_t)1 * V_];
  float cur1 = g1[(size_t)2 * V_];
  float cur2 = g1[(size_t)3 * V_];
  float cur3 = g1[(size_t)4 * V_];
  float cb0 = 0.f, cb1 = 0.f, cb2 = 0.f, cb3 = 0.f;
  if (two) {
    cb0 = gp[(size_t)1 * V_];
    cb1 = gp[(size_t)2 * V_];
    cb2 = gp[(size_t)3 * V_];
    cb3 = gp[(size_t)4 * V_];
  }

#define STEP(tt, lpv, lpb)                                              \
  {                                                                     \
    if ((tt) < len) {                                                   \
      float* bR = (((tt) & 1) ? As[0] : As[1]);                         \
      float* bW = (((tt) & 1) ? As[1] : As[0]);                         \
      float a0 = bR[s + 2];                                             \
      float a1 = bR[s + 1];                                             \
      float a2 = bR[s];                                                 \
      a2 = skip ? a2 : NEG_;                                            \
      float mx = fmaxf(fmaxf(a0, a1), a2);                              \
      float sum = ex2(a0 - mx) + ex2(a1 - mx) + ex2(a2 - mx);           \
      bW[s + 2] = mx + lg2(sum) + (lpv)*L2E;                            \
      if (two) {                                                        \
        float b0 = bR[514];                                             \
        float b1 = bR[513];                                             \
        float m2 = fmaxf(b0, b1);                                       \
        bW[514] = m2 + lg2(ex2(b0 - m2) + ex2(b1 - m2)) + (lpb)*L2E;    \
      }                                                                 \
    }                                                                   \
    __syncthreads();                                                    \
  }

  for (int tc = 1; tc < len; tc += 4) {
    const int tn = tc + 4;
    // prefetch next chunk (guarded; value unused when t >= len)
    float nx0 = (tn + 0 < T_) ? g1[(size_t)(tn + 0) * V_] : 0.f;
    float nx1 = (tn + 1 < T_) ? g1[(size_t)(tn + 1) * V_] : 0.f;
    float nx2 = (tn + 2 < T_) ? g1[(size_t)(tn + 2) * V_] : 0.f;
    float nx3 = (tn + 3 < T_) ? g1[(size_t)(tn + 3) * V_] : 0.f;
    float nb0 = 0.f, nb1 = 0.f, nb2 = 0.f, nb3 = 0.f;
    if (two) {
      nb0 = (tn + 0 < T_) ? gp[(size_t)(tn + 0) * V_] : 0.f;
      nb1 = (tn + 1 < T_) ? gp[(size_t)(tn + 1) * V_] : 0.f;
      nb2 = (tn + 2 < T_) ? gp[(size_t)(tn + 2) * V_] : 0.f;
      nb3 = (tn + 3 < T_) ? gp[(size_t)(tn + 3) * V_] : 0.f;
    }

    STEP(tc + 0, cur0, cb0);
    STEP(tc + 1, cur1, cb1);
    STEP(tc + 2, cur2, cb2);
    STEP(tc + 3, cur3, cb3);

    cur0 = nx0; cur1 = nx1; cur2 = nx2; cur3 = nx3;
    cb0 = nb0; cb1 = nb1; cb2 = nb2; cb3 = nb3;
  }
#undef STEP

  if (tid == 0) {
    // after last executed step t = len-1, alpha lives in As[(len-1)&1]
    const float* bF = ((len - 1) & 1) ? As[1] : As[0];
    const int e = 2 * tl;
    float aL = bF[e + 2];
    float aP = bF[e + 1];
    float mx = fmaxf(aL, aP);
    float l2v = mx + lg2(ex2(aL - mx) + ex2(aP - mx));
    float loss = -0.69314718055994531f * l2v;  // back to ln domain, negate
    loss = (loss < 1e29f) ? loss : 0.0f;       // zero_infinity
    atomicAdd(out, loss / ((float)tl * (float)B_));
  }
}

extern "C" void kernel_launch(void* const* d_in, const int* in_sizes, int n_in,
                              void* d_out, int out_size, void* d_ws, size_t ws_size,
                              hipStream_t stream) {
  const float* lp = (const float*)d_in[0];
  const int* tgt = (const int*)d_in[1];
  const int* il = (const int*)d_in[2];
  const int* tlenp = (const int*)d_in[3];
  float* out = (float*)d_out;

  ctc_zero<<<1, 1, 0, stream>>>(out);
  ctc_fwd<<<B_, 512, 0, stream>>>(lp, tgt, il, tlenp, out);
}

// Round 6
// 423.475 us; speedup vs baseline: 1.2218x; 1.2218x over previous
//
#include <hip/hip_runtime.h>

#define B_ 32
#define T_ 1024
#define V_ 1024
#define L_ 256
#define S_ 513
#define NEG_ (-1e30f)

#if __has_builtin(__builtin_amdgcn_exp2f)
__device__ __forceinline__ float ex2(float x) { return __builtin_amdgcn_exp2f(x); }
#else
__device__ __forceinline__ float ex2(float x) { return exp2f(x); }
#endif
#if __has_builtin(__builtin_amdgcn_logf)
__device__ __forceinline__ float lg2(float x) { return __builtin_amdgcn_logf(x); }
#else
__device__ __forceinline__ float lg2(float x) { return log2f(x); }
#endif

__global__ void ctc_zero(float* out) { out[0] = 0.0f; }

// ---------------------------------------------------------------------------
// Pre-pass: gather (log2 domain, no exp). One block per (b,t) row.
//   g2[bt][li] = lp[b][t][targets[b][li]] * log2(e)   li = 0..255 (odd states)
//   pb[bt]     = lp[b][t][0]              * log2(e)   (blank states)
// ---------------------------------------------------------------------------
__global__ __launch_bounds__(256) void ctc_gather(const float* __restrict__ lp,
                                                  const int* __restrict__ tgt,
                                                  float* __restrict__ g2,
                                                  float* __restrict__ pb) {
  const int bt = blockIdx.x;
  const int b = bt >> 10;  // T_=1024
  const int li = threadIdx.x;
  const float* row = lp + (size_t)bt * V_;
  const float L2E = 1.4426950408889634f;
  const int col = tgt[b * L_ + li];
  g2[(size_t)bt * 256 + li] = row[col] * L2E;
  if (li == 0) pb[bt] = row[0] * L2E;
}

// ---------------------------------------------------------------------------
// Exact logsumexp with minimal transcendental count:
//   lse2 = max + log2(1 + 2^(-|x-y|))                       (2 trans ops)
//   lse3 = max3 + log2(1 + 2^(med3-max3) + 2^(min3-max3))   (3 trans ops)
// Both are exact reorganizations (2^0 = 1 term folded out).
// ---------------------------------------------------------------------------
__device__ __forceinline__ float lse2(float x, float y) {
  const float m = fmaxf(x, y);
  return m + lg2(1.0f + ex2(-fabsf(x - y)));
}
#if __has_builtin(__builtin_amdgcn_fmed3f)
__device__ __forceinline__ float med3f(float x, float y, float z) {
  return __builtin_amdgcn_fmed3f(x, y, z);
}
#else
__device__ __forceinline__ float med3f(float x, float y, float z) {
  return fmaxf(fminf(fmaxf(x, y), z), fminf(x, y));  // exact median network
}
#endif
__device__ __forceinline__ float lse3(float x, float y, float z) {
  const float mx = fmaxf(fmaxf(x, y), z);
  const float md = med3f(x, y, z);
  const float mn = fminf(fminf(x, y), z);
  return mx + lg2(1.0f + ex2(md - mx) + ex2(mn - mx));
}

// ---------------------------------------------------------------------------
// Serial recursion: one wave per batch element, lane l owns states 8l..8l+7
// (log2-domain alpha in registers), lane 63 also owns state 512. Zero
// barriers; the only cross-lane dependency is one __shfl_up per step.
// Triple-buffered 8-row prefetch: issue-to-use distance ~16 steps.
// ---------------------------------------------------------------------------
__device__ __forceinline__ void rstep(float (&a)[8], float& a8, float4 po, float pb,
                                      float4 sm, int l, bool last) {
  float up1 = __shfl_up(a[7], 1);  // old alpha[8l-1] from left lane
  if (l == 0) up1 = NEG_;
  float n0 = lse2(a[0], up1) + pb;
  float n1 = lse3(a[1], a[0], (sm.x != 0.f) ? up1 : NEG_) + po.x;
  float n2 = lse2(a[2], a[1]) + pb;
  float n3 = lse3(a[3], a[2], (sm.y != 0.f) ? a[1] : NEG_) + po.y;
  float n4 = lse2(a[4], a[3]) + pb;
  float n5 = lse3(a[5], a[4], (sm.z != 0.f) ? a[3] : NEG_) + po.z;
  float n6 = lse2(a[6], a[5]) + pb;
  float n7 = lse3(a[7], a[6], (sm.w != 0.f) ? a[5] : NEG_) + po.w;
  float n8 = lse2(a8, a[7]) + pb;  // state 512 (blank), lane 63 only
  a[0] = n0; a[1] = n1; a[2] = n2; a[3] = n3;
  a[4] = n4; a[5] = n5; a[6] = n6; a[7] = n7;
  if (last) a8 = n8;
}

__global__ __launch_bounds__(64) void ctc_rec(const float* __restrict__ g2,
                                              const float* __restrict__ pbg,
                                              const int* __restrict__ tgt,
                                              const int* __restrict__ ilen,
                                              const int* __restrict__ tlen,
                                              float* __restrict__ out) {
  __shared__ float fin[513];
  const int b = blockIdx.x;
  const int l = threadIdx.x;  // 0..63
  const int len = ilen[b];
  const int tl = tlen[b];
  const bool last = (l == 63);
  const float* gb2 = g2 + (size_t)b * T_ * 256;
  const float* PBb = pbg + (size_t)b * T_;
  const int* tb = tgt + b * L_;

  // skip masks for owned odd states s = 8l+{1,3,5,7} -> label idx li = 4l+{0..3}
  float4 sm;
  {
    const int li0 = l << 2;
    const int t0 = tb[li0];
    const int t1 = tb[li0 + 1];
    const int t2 = tb[li0 + 2];
    const int t3 = tb[li0 + 3];
    sm.x = (li0 >= 1 && t0 != tb[li0 >= 1 ? li0 - 1 : 0]) ? 1.f : 0.f;
    sm.y = (t1 != t0) ? 1.f : 0.f;
    sm.z = (t2 != t1) ? 1.f : 0.f;
    sm.w = (t3 != t2) ? 1.f : 0.f;
  }

  float a[8];
#pragma unroll
  for (int k = 0; k < 8; ++k) a[k] = NEG_;
  float a8 = NEG_;

  // t = 0 init: alpha[0] = lp_blank(0), alpha[1] = lp_y1(0)  (log2 domain)
  if (l == 0) {
    a[0] = PBb[0];
    a[1] = gb2[0];
  }

  // three named 8-row buffers (static indexing only -- runtime-indexed
  // register arrays go to scratch). Reads may overrun past row T_-1 for
  // late tc; they stay inside g2/pb(+pad) allocations, values unused.
  float4 C0[8], C1[8], C2[8];
  float P0[8], P1[8], P2[8];

#define ISSUE(Cb, Pb, r0)                                                    \
  {                                                                          \
    _Pragma("unroll") for (int i = 0; i < 8; ++i) {                          \
      Cb[i] = *(const float4*)(gb2 + (size_t)((r0) + i) * 256 + (l << 2));   \
      Pb[i] = PBb[(r0) + i];                                                 \
    }                                                                        \
  }
#define CONSUME8(Cb, Pb)                                                     \
  {                                                                          \
    _Pragma("unroll") for (int i = 0; i < 8; ++i)                            \
        rstep(a, a8, Cb[i], Pb[i], sm, l, last);                             \
  }
#define REMAINDER(Cb, Pb)                                                    \
  {                                                                          \
    _Pragma("unroll") for (int i = 0; i < 8; ++i)                            \
        if (tc + i < len) rstep(a, a8, Cb[i], Pb[i], sm, l, last);           \
  }
#define PHASE(Ccur, Pcur, Cnxt, Pnxt)                                        \
  {                                                                          \
    if (tc + 7 >= len) { REMAINDER(Ccur, Pcur); goto done; }                 \
    ISSUE(Cnxt, Pnxt, tc + 16);                                              \
    CONSUME8(Ccur, Pcur);                                                    \
    tc += 8;                                                                 \
  }

  ISSUE(C0, P0, 1);
  ISSUE(C1, P1, 9);
  int tc = 1;
  for (;;) {
    PHASE(C0, P0, C2, P2);
    PHASE(C1, P1, C0, P0);
    PHASE(C2, P2, C1, P1);
  }
done:
#undef PHASE
#undef REMAINDER
#undef CONSUME8
#undef ISSUE

  // epilogue: loss = -ln2 * logaddexp2(alpha[2tl], alpha[2tl-1])
#pragma unroll
  for (int k = 0; k < 8; ++k) fin[(l << 3) + k] = a[k];
  if (last) fin[512] = a8;
  __syncthreads();
  if (l == 0) {
    const int e2 = 2 * tl;
    const float l2v = lse2(fin[e2], fin[e2 - 1]);
    float loss = -0.69314718055994531f * l2v;
    if (!(loss < 1e29f)) loss = 0.0f;  // zero_infinity (inf/NaN -> 0)
    atomicAdd(out, loss / ((float)tl * (float)B_));
  }
}

// ---------------------------------------------------------------------------
// Fallback (round-1 kernel, known-good, 517us) used only if ws too small.
// ---------------------------------------------------------------------------
__global__ __launch_bounds__(512) void ctc_fwd(const float* __restrict__ lp,
                                               const int* __restrict__ tgt,
                                               const int* __restrict__ ilen,
                                               const int* __restrict__ tlen,
                                               float* __restrict__ out) {
  __shared__ float As[2][520];
  const int b = blockIdx.x;
  const int tid = threadIdx.x;
  const int len = ilen[b];
  const int tl = tlen[b];
  const float* gp = lp + (size_t)b * T_ * V_;
  const int s = tid;
  const bool two = (tid == 511);
  int col;
  bool skip;
  if (s & 1) {
    const int l = s >> 1;
    col = tgt[b * L_ + l];
    skip = (s >= 3) && (col != tgt[b * L_ + l - 1]);
  } else {
    col = 0;
    skip = false;
  }
  const float L2E = 1.4426950408889634f;
  As[0][tid + 2] = (s < 2) ? L2E * gp[col] : NEG_;
  if (two) As[0][514] = NEG_;
  if (tid < 2) { As[0][tid] = NEG_; As[1][tid] = NEG_; }
  __syncthreads();
  const float* g1 = gp + col;
#define STEP(tt, lpv, lpb)                                              \
  {                                                                     \
    if ((tt) < len) {                                                   \
      float* bR = (((tt) & 1) ? As[0] : As[1]);                         \
      float* bW = (((tt) & 1) ? As[1] : As[0]);                         \
      float a0 = bR[s + 2];                                             \
      float a1 = bR[s + 1];                                             \
      float a2 = bR[s];                                                 \
      a2 = skip ? a2 : NEG_;                                            \
      float mx = fmaxf(fmaxf(a0, a1), a2);                              \
      float sum = ex2(a0 - mx) + ex2(a1 - mx) + ex2(a2 - mx);           \
      bW[s + 2] = mx + lg2(sum) + (lpv)*L2E;                            \
      if (two) {                                                        \
        float b0 = bR[514];                                             \
        float b1 = bR[513];                                             \
        float m2 = fmaxf(b0, b1);                                       \
        bW[514] = m2 + lg2(ex2(b0 - m2) + ex2(b1 - m2)) + (lpb)*L2E;    \
      }                                                                 \
    }                                                                   \
    __syncthreads();                                                    \
  }
  float cur0 = g1[(size_t)1 * V_], cur1 = g1[(size_t)2 * V_];
  float cur2 = g1[(size_t)3 * V_], cur3 = g1[(size_t)4 * V_];
  float cb0 = 0.f, cb1 = 0.f, cb2 = 0.f, cb3 = 0.f;
  if (two) {
    cb0 = gp[(size_t)1 * V_]; cb1 = gp[(size_t)2 * V_];
    cb2 = gp[(size_t)3 * V_]; cb3 = gp[(size_t)4 * V_];
  }
  for (int tc = 1; tc < len; tc += 4) {
    const int tn = tc + 4;
    float nx0 = (tn + 0 < T_) ? g1[(size_t)(tn + 0) * V_] : 0.f;
    float nx1 = (tn + 1 < T_) ? g1[(size_t)(tn + 1) * V_] : 0.f;
    float nx2 = (tn + 2 < T_) ? g1[(size_t)(tn + 2) * V_] : 0.f;
    float nx3 = (tn + 3 < T_) ? g1[(size_t)(tn + 3) * V_] : 0.f;
    float nb0 = 0.f, nb1 = 0.f, nb2 = 0.f, nb3 = 0.f;
    if (two) {
      nb0 = (tn + 0 < T_) ? gp[(size_t)(tn + 0) * V_] : 0.f;
      nb1 = (tn + 1 < T_) ? gp[(size_t)(tn + 1) * V_] : 0.f;
      nb2 = (tn + 2 < T_) ? gp[(size_t)(tn + 2) * V_] : 0.f;
      nb3 = (tn + 3 < T_) ? gp[(size_t)(tn + 3) * V_] : 0.f;
    }
    STEP(tc + 0, cur0, cb0);
    STEP(tc + 1, cur1, cb1);
    STEP(tc + 2, cur2, cb2);
    STEP(tc + 3, cur3, cb3);
    cur0 = nx0; cur1 = nx1; cur2 = nx2; cur3 = nx3;
    cb0 = nb0; cb1 = nb1; cb2 = nb2; cb3 = nb3;
  }
#undef STEP
  if (tid == 0) {
    const float* bF = ((len - 1) & 1) ? As[1] : As[0];
    const int e = 2 * tl;
    float aL = bF[e + 2];
    float aP = bF[e + 1];
    float mx = fmaxf(aL, aP);
    float l2v = mx + lg2(ex2(aL - mx) + ex2(aP - mx));
    float loss = -0.69314718055994531f * l2v;
    loss = (loss < 1e29f) ? loss : 0.0f;
    atomicAdd(out, loss / ((float)tl * (float)B_));
  }
}

extern "C" void kernel_launch(void* const* d_in, const int* in_sizes, int n_in,
                              void* d_out, int out_size, void* d_ws, size_t ws_size,
                              hipStream_t stream) {
  const float* lp = (const float*)d_in[0];
  const int* tgt = (const int*)d_in[1];
  const int* il = (const int*)d_in[2];
  const int* tlenp = (const int*)d_in[3];
  float* out = (float*)d_out;

  const size_t g2_bytes = (size_t)B_ * T_ * 256 * 4;   // 32 MiB
  const size_t pb_bytes = ((size_t)B_ * T_ + 64) * 4;  // + prefetch-overrun pad
  ctc_zero<<<1, 1, 0, stream>>>(out);
  if (ws_size >= g2_bytes + pb_bytes) {
    float* g2 = (float*)d_ws;
    float* pb = (float*)((char*)d_ws + g2_bytes);
    ctc_gather<<<B_ * T_, 256, 0, stream>>>(lp, tgt, g2, pb);
    ctc_rec<<<B_, 64, 0, stream>>>(g2, pb, tgt, il, tlenp, out);
  } else {
    ctc_fwd<<<B_, 512, 0, stream>>>(lp, tgt, il, tlenp, out);
  }
}

// Round 8
// 310.753 us; speedup vs baseline: 1.6649x; 1.3627x over previous
//
#include <hip/hip_runtime.h>

#define B_ 32
#define T_ 1024
#define V_ 1024
#define L_ 256
#define S_ 513
#define NEG_ (-1e30f)

#if __has_builtin(__builtin_amdgcn_exp2f)
__device__ __forceinline__ float ex2(float x) { return __builtin_amdgcn_exp2f(x); }
#else
__device__ __forceinline__ float ex2(float x) { return exp2f(x); }
#endif
#if __has_builtin(__builtin_amdgcn_logf)
__device__ __forceinline__ float lg2(float x) { return __builtin_amdgcn_logf(x); }
#else
__device__ __forceinline__ float lg2(float x) { return log2f(x); }
#endif

__global__ void ctc_zero(float* out) { out[0] = 0.0f; }

// ---------------------------------------------------------------------------
// Pre-pass: gather + exp (linear domain). One block per (b,t) row.
// Coalesced: stage the 4KB row into LDS (one float4/thread), gather from LDS.
//   g2[bt][li] = exp(lp[b][t][targets[b][li]])   li = 0..255 (odd states)
//   pb[bt]     = exp(lp[b][t][0])                (blank states)
// exp(lp) >= e^-11 for log-softmax of N(0,1) logits -> no underflow.
// ---------------------------------------------------------------------------
__global__ __launch_bounds__(256) void ctc_gather(const float* __restrict__ lp,
                                                  const int* __restrict__ tgt,
                                                  float* __restrict__ g2,
                                                  float* __restrict__ pb) {
  __shared__ float row_s[V_];
  const int bt = blockIdx.x;
  const int b = bt >> 10;  // T_=1024
  const int li = threadIdx.x;
  const float* row = lp + (size_t)bt * V_;
  const float L2E = 1.4426950408889634f;

  ((float4*)row_s)[li] = ((const float4*)row)[li];  // coalesced 16B/thread
  const int col = tgt[b * L_ + li];                 // overlaps LDS latency
  __syncthreads();

  g2[(size_t)bt * 256 + li] = ex2(row_s[col] * L2E);
  if (li == 0) pb[bt] = ex2(row_s[0] * L2E);
}

__device__ __forceinline__ float lse2(float x, float y) {  // log2 domain, exact
  const float m = fmaxf(x, y);
  return m + lg2(1.0f + ex2(-fabsf(x - y)));
}

// ---------------------------------------------------------------------------
// Serial recursion, LINEAR domain with per-lane block-floating-point.
// One wave per batch element; lane l owns states 8l..8l+7 (lane 63 also owns
// state 512). Lane state: stored[9] + int sh, true_alpha = stored * 2^sh.
//  - per-step cross-lane handoff: shfl a[7] and sh; re-frame via exact ldexp.
//    new_sh = active ? max(sh, shs-(251-e7)) : shs   guarantees up1 <= 2^124
//    (no inf) and subsumes activation adoption (a7s=0 -> e7=0 -> no adopt).
//    Every lane applies stored*=2^(sh-new_sh); sh=new_sh (value-preserving
//    for ANY new_sh; only drops mass that is >=2^150 below the lane scale,
//    which is correct to drop).
//  - per-lane rescale to 2^100 every 8 steps (no cross-lane reduction):
//    worst 8-step decay 2^-122 keeps stored max >= 2^-22; within-lane spread
//    (~2^77 bound via a0 >= up1*pb refresh) stays above denormals.
// All scale ops are powers of 2 => exact; only fp32 add/mul rounding remains
// (~1e-4 nats over 1024 steps). ~22 VALU + 10 ldexp + 2 shfl per step.
// ---------------------------------------------------------------------------
__device__ __forceinline__ void rstep_lin(float (&a)[8], float& a8, int& sh,
                                          float4 po, float pb, float4 sm,
                                          int l, bool last) {
  float a7s = __shfl_up(a[7], 1);
  int shs = __shfl_up(sh, 1);
  const bool active = (a[0] != 0.f);
  const int e7 = (int)((__float_as_uint(a7s) >> 23) & 0xffu);
  const int cap = shs - (251 - e7);          // adopt only enough to fit 2^124
  const int cand = (cap > sh) ? cap : sh;    // max(sh, cap)
  const int new_sh = active ? cand : shs;    // inactive: adopt src frame
  const int dself = sh - new_sh;             // <= 0 for active; exact scaling
  const int din = shs - new_sh;              // e7+din <= 251 -> up1 finite
  sh = new_sh;
  float up1 = ldexpf(a7s, din);
  if (l == 0) up1 = 0.f;
#pragma unroll
  for (int k = 0; k < 8; ++k) a[k] = ldexpf(a[k], dself);
  a8 = ldexpf(a8, dself);

  float n0 = (a[0] + up1) * pb;
  float n1 = fmaf(sm.x, up1, a[1] + a[0]) * po.x;
  float n2 = (a[2] + a[1]) * pb;
  float n3 = fmaf(sm.y, a[1], a[3] + a[2]) * po.y;
  float n4 = (a[4] + a[3]) * pb;
  float n5 = fmaf(sm.z, a[3], a[5] + a[4]) * po.z;
  float n6 = (a[6] + a[5]) * pb;
  float n7 = fmaf(sm.w, a[5], a[7] + a[6]) * po.w;
  float n8 = (a8 + a[7]) * pb;  // state 512 (blank), lane 63 only
  a[0] = n0; a[1] = n1; a[2] = n2; a[3] = n3;
  a[4] = n4; a[5] = n5; a[6] = n6; a[7] = n7;
  if (last) a8 = n8;
}

__device__ __forceinline__ void rescale_lin(float (&a)[8], float& a8, int& sh) {
  float m = fmaxf(fmaxf(fmaxf(a[0], a[1]), fmaxf(a[2], a[3])),
                  fmaxf(fmaxf(a[4], a[5]), fmaxf(a[6], a[7])));
  m = fmaxf(m, a8);
  const int e = (int)((__float_as_uint(m) >> 23) & 0xffu);
  const int d = (m > 0.f) ? (227 - e) : 0;  // bring lane max to ~2^100
#pragma unroll
  for (int k = 0; k < 8; ++k) a[k] = ldexpf(a[k], d);
  a8 = ldexpf(a8, d);
  sh -= d;
}

__global__ __launch_bounds__(64) void ctc_rec(const float* __restrict__ g2,
                                              const float* __restrict__ pbg,
                                              const int* __restrict__ tgt,
                                              const int* __restrict__ ilen,
                                              const int* __restrict__ tlen,
                                              float* __restrict__ out) {
  __shared__ float fin[513];
  const int b = blockIdx.x;
  const int l = threadIdx.x;  // 0..63
  const int len = ilen[b];
  const int tl = tlen[b];
  const bool last = (l == 63);
  const float* gb2 = g2 + (size_t)b * T_ * 256;
  const float* PBb = pbg + (size_t)b * T_;
  const int* tb = tgt + b * L_;

  // skip masks for owned odd states s = 8l+{1,3,5,7} -> label idx li = 4l+{0..3}
  float4 sm;
  {
    const int li0 = l << 2;
    const int t0 = tb[li0];
    const int t1 = tb[li0 + 1];
    const int t2 = tb[li0 + 2];
    const int t3 = tb[li0 + 3];
    sm.x = (li0 >= 1 && t0 != tb[li0 >= 1 ? li0 - 1 : 0]) ? 1.f : 0.f;
    sm.y = (t1 != t0) ? 1.f : 0.f;
    sm.z = (t2 != t1) ? 1.f : 0.f;
    sm.w = (t3 != t2) ? 1.f : 0.f;
  }

  float a[8];
#pragma unroll
  for (int k = 0; k < 8; ++k) a[k] = 0.f;
  float a8 = 0.f;
  int sh = 0;

  // t = 0 init (linear): alpha[0] = p_blank(0), alpha[1] = p_y1(0)
  if (l == 0) {
    a[0] = PBb[0];
    a[1] = gb2[0];
  }

  // three named 8-row buffers (static indexing only). Reads may overrun past
  // row T_-1 for late tc; they stay inside g2/pb(+pad), values unused.
  float4 C0[8], C1[8], C2[8];
  float P0[8], P1[8], P2[8];

#define ISSUE(Cb, Pb, r0)                                                    \
  {                                                                          \
    _Pragma("unroll") for (int i = 0; i < 8; ++i) {                          \
      Cb[i] = *(const float4*)(gb2 + (size_t)((r0) + i) * 256 + (l << 2));   \
      Pb[i] = PBb[(r0) + i];                                                 \
    }                                                                        \
  }
#define CONSUME8(Cb, Pb)                                                     \
  {                                                                          \
    _Pragma("unroll") for (int i = 0; i < 8; ++i)                            \
        rstep_lin(a, a8, sh, Cb[i], Pb[i], sm, l, last);                     \
  }
#define REMAINDER(Cb, Pb)                                                    \
  {                                                                          \
    _Pragma("unroll") for (int i = 0; i < 8; ++i)                            \
        if (tc + i < len) rstep_lin(a, a8, sh, Cb[i], Pb[i], sm, l, last);   \
  }
#define PHASE(Ccur, Pcur, Cnxt, Pnxt)                                        \
  {                                                                          \
    if (tc + 7 >= len) { REMAINDER(Ccur, Pcur); goto done; }                 \
    ISSUE(Cnxt, Pnxt, tc + 16);                                              \
    CONSUME8(Ccur, Pcur);                                                    \
    rescale_lin(a, a8, sh);                                                  \
    tc += 8;                                                                 \
  }

  ISSUE(C0, P0, 1);
  ISSUE(C1, P1, 9);
  int tc = 1;
  for (;;) {
    PHASE(C0, P0, C2, P2);
    PHASE(C1, P1, C0, P0);
    PHASE(C2, P2, C1, P1);
  }
done:
#undef PHASE
#undef REMAINDER
#undef CONSUME8
#undef ISSUE

  // epilogue: fin[s] = log2(true alpha) = log2(stored) + sh   (per-lane sh)
#pragma unroll
  for (int k = 0; k < 8; ++k)
    fin[(l << 3) + k] = fmaxf(lg2(a[k]) + (float)sh, NEG_);
  if (last) fin[512] = fmaxf(lg2(a8) + (float)sh, NEG_);
  __syncthreads();
  if (l == 0) {
    const int e2 = 2 * tl;
    const float l2v = lse2(fin[e2], fin[e2 - 1]);
    float loss = -0.69314718055994531f * l2v;
    if (!(loss < 1e29f)) loss = 0.0f;  // zero_infinity (inf/NaN -> 0)
    atomicAdd(out, loss / ((float)tl * (float)B_));
  }
}

// ---------------------------------------------------------------------------
// Fallback (round-1 kernel, known-good, 517us) used only if ws too small.
// ---------------------------------------------------------------------------
__global__ __launch_bounds__(512) void ctc_fwd(const float* __restrict__ lp,
                                               const int* __restrict__ tgt,
                                               const int* __restrict__ ilen,
                                               const int* __restrict__ tlen,
                                               float* __restrict__ out) {
  __shared__ float As[2][520];
  const int b = blockIdx.x;
  const int tid = threadIdx.x;
  const int len = ilen[b];
  const int tl = tlen[b];
  const float* gp = lp + (size_t)b * T_ * V_;
  const int s = tid;
  const bool two = (tid == 511);
  int col;
  bool skip;
  if (s & 1) {
    const int l = s >> 1;
    col = tgt[b * L_ + l];
    skip = (s >= 3) && (col != tgt[b * L_ + l - 1]);
  } else {
    col = 0;
    skip = false;
  }
  const float L2E = 1.4426950408889634f;
  As[0][tid + 2] = (s < 2) ? L2E * gp[col] : NEG_;
  if (two) As[0][514] = NEG_;
  if (tid < 2) { As[0][tid] = NEG_; As[1][tid] = NEG_; }
  __syncthreads();
  const float* g1 = gp + col;
#define STEP(tt, lpv, lpb)                                              \
  {                                                                     \
    if ((tt) < len) {                                                   \
      float* bR = (((tt) & 1) ? As[0] : As[1]);                         \
      float* bW = (((tt) & 1) ? As[1] : As[0]);                         \
      float a0 = bR[s + 2];                                             \
      float a1 = bR[s + 1];                                             \
      float a2 = bR[s];                                                 \
      a2 = skip ? a2 : NEG_;                                            \
      float mx = fmaxf(fmaxf(a0, a1), a2);                              \
      float sum = ex2(a0 - mx) + ex2(a1 - mx) + ex2(a2 - mx);           \
      bW[s + 2] = mx + lg2(sum) + (lpv)*L2E;                            \
      if (two) {                                                        \
        float b0 = bR[514];                                             \
        float b1 = bR[513];                                             \
        float m2 = fmaxf(b0, b1);                                       \
        bW[514] = m2 + lg2(ex2(b0 - m2) + ex2(b1 - m2)) + (lpb)*L2E;    \
      }                                                                 \
    }                                                                   \
    __syncthreads();                                                    \
  }
  float cur0 = g1[(size_t)1 * V_], cur1 = g1[(size_t)2 * V_];
  float cur2 = g1[(size_t)3 * V_], cur3 = g1[(size_t)4 * V_];
  float cb0 = 0.f, cb1 = 0.f, cb2 = 0.f, cb3 = 0.f;
  if (two) {
    cb0 = gp[(size_t)1 * V_]; cb1 = gp[(size_t)2 * V_];
    cb2 = gp[(size_t)3 * V_]; cb3 = gp[(size_t)4 * V_];
  }
  for (int tc = 1; tc < len; tc += 4) {
    const int tn = tc + 4;
    float nx0 = (tn + 0 < T_) ? g1[(size_t)(tn + 0) * V_] : 0.f;
    float nx1 = (tn + 1 < T_) ? g1[(size_t)(tn + 1) * V_] : 0.f;
    float nx2 = (tn + 2 < T_) ? g1[(size_t)(tn + 2) * V_] : 0.f;
    float nx3 = (tn + 3 < T_) ? g1[(size_t)(tn + 3) * V_] : 0.f;
    float nb0 = 0.f, nb1 = 0.f, nb2 = 0.f, nb3 = 0.f;
    if (two) {
      nb0 = (tn + 0 < T_) ? gp[(size_t)(tn + 0) * V_] : 0.f;
      nb1 = (tn + 1 < T_) ? gp[(size_t)(tn + 1) * V_] : 0.f;
      nb2 = (tn + 2 < T_) ? gp[(size_t)(tn + 2) * V_] : 0.f;
      nb3 = (tn + 3 < T_) ? gp[(size_t)(tn + 3) * V_] : 0.f;
    }
    STEP(tc + 0, cur0, cb0);
    STEP(tc + 1, cur1, cb1);
    STEP(tc + 2, cur2, cb2);
    STEP(tc + 3, cur3, cb3);
    cur0 = nx0; cur1 = nx1; cur2 = nx2; cur3 = nx3;
    cb0 = nb0; cb1 = nb1; cb2 = nb2; cb3 = nb3;
  }
#undef STEP
  if (tid == 0) {
    const float* bF = ((len - 1) & 1) ? As[1] : As[0];
    const int e = 2 * tl;
    float aL = bF[e + 2];
    float aP = bF[e + 1];
    float mx = fmaxf(aL, aP);
    float l2v = mx + lg2(ex2(aL - mx) + ex2(aP - mx));
    float loss = -0.69314718055994531f * l2v;
    loss = (loss < 1e29f) ? loss : 0.0f;
    atomicAdd(out, loss / ((float)tl * (float)B_));
  }
}

extern "C" void kernel_launch(void* const* d_in, const int* in_sizes, int n_in,
                              void* d_out, int out_size, void* d_ws, size_t ws_size,
                              hipStream_t stream) {
  const float* lp = (const float*)d_in[0];
  const int* tgt = (const int*)d_in[1];
  const int* il = (const int*)d_in[2];
  const int* tlenp = (const int*)d_in[3];
  float* out = (float*)d_out;

  const size_t g2_bytes = (size_t)B_ * T_ * 256 * 4;   // 32 MiB
  const size_t pb_bytes = ((size_t)B_ * T_ + 64) * 4;  // + prefetch-overrun pad
  ctc_zero<<<1, 1, 0, stream>>>(out);
  if (ws_size >= g2_bytes + pb_bytes) {
    float* g2 = (float*)d_ws;
    float* pb = (float*)((char*)d_ws + g2_bytes);
    ctc_gather<<<B_ * T_, 256, 0, stream>>>(lp, tgt, g2, pb);
    ctc_rec<<<B_, 64, 0, stream>>>(g2, pb, tgt, il, tlenp, out);
  } else {
    ctc_fwd<<<B_, 512, 0, stream>>>(lp, tgt, il, tlenp, out);
  }
}